// Round 6
// baseline (2863.744 us; speedup 1.0000x reference)
//
#include <hip/hip_runtime.h>

typedef unsigned short u16;
typedef _Float16 f16;
typedef __attribute__((ext_vector_type(4))) float f32x4;
typedef __attribute__((ext_vector_type(8))) _Float16 f16x8;
typedef __attribute__((ext_vector_type(8))) unsigned short u16x8;

#define NIMG 8
#define HH 100
#define WW 152
#define HP 102
#define WP 154
#define NPIX (NIMG*HH*WW)                       // 121600
#define ACT_ELEMS ((size_t)NIMG*HP*WP*256)      // 32,169,984
#define ACT_BYTES (ACT_ELEMS*2)

__device__ __forceinline__ u16 f2h(float x){
    f16 h = (f16)x;                       // v_cvt_f16_f32, RNE
    return __builtin_bit_cast(u16, h);
}

__device__ __forceinline__ void g2l16(const u16* g, u16* l){
    __builtin_amdgcn_global_load_lds((const __attribute__((address_space(1))) unsigned int*)g,
                                     (__attribute__((address_space(3))) unsigned int*)l, 16, 0, 0);
}

// ---------------- border zeroing (pads of both ping-pong activation buffers) ----------------
__global__ void zero_borders(u16* A, u16* B){
    int id = blockIdx.x*256 + threadIdx.x;            // 8*508*32 = 130048 exact
    int ch = id & 31; int t = id >> 5;
    int pb = t % 508; int nimg = t / 508;
    int hp, wp;
    if (pb < 154)      { hp = 0;            wp = pb; }
    else if (pb < 308) { hp = 101;          wp = pb - 154; }
    else if (pb < 408) { hp = pb - 308 + 1; wp = 0; }
    else               { hp = pb - 408 + 1; wp = 153; }
    size_t off = ((size_t)((nimg*HP + hp)*WP + wp))*256 + ch*8;
    u16x8 z = {};
    *(u16x8*)(A+off) = z; *(u16x8*)(B+off) = z;
}

// ---------------- NCHW fp32 feature -> padded NHWC fp16 ----------------
__global__ void feat2act(const float* __restrict__ F, u16* __restrict__ D){
    __shared__ float t[64][65];
    int bid = blockIdx.x;
    int wb = bid % 3; bid /= 3;
    int cb = bid & 3; bid >>= 2;
    int h = bid % 100; int nimg = bid / 100;
    int c0 = cb*64, w0 = wb*64;
    int tid = threadIdx.x;
    int cl = tid >> 6;        // 0..3
    int wl = tid & 63;
    #pragma unroll
    for (int rr=0; rr<16; ++rr){
        int c = rr*4 + cl;
        int w = w0 + wl;
        float v = 0.f;
        if (w < WW) v = F[ ((size_t)((nimg*256 + c0 + c)*HH + h))*WW + w ];
        t[c][wl] = v;
    }
    __syncthreads();
    int wl2 = tid >> 6;
    int cl2 = tid & 63;
    #pragma unroll
    for (int rr=0; rr<16; ++rr){
        int w = rr*4 + wl2;
        if (w0 + w < WW){
            size_t dst = ((size_t)((nimg*HP + h + 1)*WP + (w0 + w + 1)))*256 + c0 + cl2;
            D[dst] = f2h(t[cl2][w]);
        }
    }
}

// ---------------- weight transforms: OIHW fp32 -> [tap][co][ci] fp16 ----------------
__global__ void wt_tower(const float* __restrict__ src, u16* __restrict__ d){
    int idx = blockIdx.x*256 + threadIdx.x;        // layers*9*256*256, exact
    int ci = idx & 255; int t = idx >> 8;
    int co = t & 255; t >>= 8;
    int tap = t % 9; int l = t / 9;
    d[idx] = f2h(src[ ((size_t)((l*256+co)*256+ci))*9 + tap ]);
}
// pred(64)+ctn(1) padded to 80 cout
__global__ void wt_predctn(const float* __restrict__ pw, const float* __restrict__ cw,
                           u16* __restrict__ d){
    int idx = blockIdx.x*256 + threadIdx.x;        // 9*80*256 = 184320 exact (720 blocks)
    int ci = idx & 255; int t = idx >> 8;
    int co = t % 80; int tap = t / 80;
    float v = 0.f;
    if (co < 64)       v = pw[ ((size_t)(co*256+ci))*9 + tap ];
    else if (co == 64) v = cw[ (size_t)ci*9 + tap ];
    d[idx] = f2h(v);
}
// score(1) padded to 16 cout
__global__ void wt_score(const float* __restrict__ sw, u16* __restrict__ d){
    int idx = blockIdx.x*256 + threadIdx.x;        // 9*16*256 = 36864 exact (144 blocks)
    int ci = idx & 255; int t = idx >> 8;
    int co = t & 15; int tap = t >> 4;
    d[idx] = f2h((co == 0) ? sw[ (size_t)ci*9 + tap ] : 0.f);
}
__global__ void prep_bias(const float* pb, const float* cb, const float* sb, float* bpc, float* bsc){
    int i = threadIdx.x;      // 128
    bpc[i] = (i < 64) ? pb[i] : ((i == 64) ? cb[0] : 0.f);
    bsc[i] = (i == 0) ? sb[0] : 0.f;
}

// ---------------- conv3x3 implicit GEMM, fp16, 128-pix M-tile, BK=64, B-in-registers ----------------
// LDS holds ONLY the A (activation) tile: [2 bufs][128 rows][64 k] fp16 = 32 KiB.
// B (weights) is L2-resident (<=1.2 MB/layer, shared by all blocks): loaded straight to
// registers one full step ahead (double reg-set, unroll-2 loop, static names).
// Sync protocol per step: ds_read A-frags -> lgkmcnt(0) -> barrier -> stage A(t+2) into
// same buf (WAR-safe) + issue B(t+1) reg loads -> MFMA (compiler's counted vmcnt covers
// B(t) reg dep; FIFO order means it also retires A(t+1)) -> vmcnt(4+2*NR) -> barrier.
// MODE 0: tower  (waves 2Mx2N, 4x4 frags, COUTP=256, relu, store padded NHWC fp16)
// MODE 1: pred+ctn head (waves 4M, 2x5 frags, COUTP=80; co<64 -> O1[pix*64+co], co==64 -> O2[pix])
// MODE 2: score head    (waves 4M, 2x1 frags, COUTP=16; co==0 -> O1[pix])
template<int MODE>
__global__ __launch_bounds__(256, 2) void conv3x3_k(
    const u16* __restrict__ Ain, const u16* __restrict__ W,
    const float* __restrict__ bias,
    u16* __restrict__ Oh,
    float* __restrict__ O1, float* __restrict__ O2,
    int NB, int COUTP)
{
    constexpr int MR = (MODE==0) ? 4 : 2;
    constexpr int NR = (MODE==0) ? 4 : ((MODE==1) ? 5 : 1);
    constexpr int VMN = 4 + 2*NR;          // end-of-step: leave stage(t+2)[4] + B(t+1)[2*NR] in flight

    __shared__ u16 lds[16384];   // 32 KiB: 2 x A[128][64] fp16
    const int tid  = threadIdx.x;
    const int lane = tid & 63;
    const int wave = tid >> 6;

    // bijective XCD swizzle (gridDim.x % 8 == 0)
    int nwg = gridDim.x;
    int bid = blockIdx.x;
    int qq  = nwg >> 3;
    int swz = (bid & 7)*qq + (bid >> 3);
    int nblk = swz % NB;
    int mblk = swz / NB;
    int nimg = mblk / 125;
    int rem  = mblk - nimg*125;
    int ht   = rem / 5;
    int wt5  = rem - ht*5;
    int h0 = ht*4, w0 = wt5*32;

    // A staging source offsets. slot s: p=s>>3 pixel-row, ch=s&7 16B chunk; chs = ch ^ (p&7).
    int aoff[4];
    #pragma unroll
    for (int it=0; it<4; ++it){
        int s = it*256 + tid;
        int p = s >> 3, ch = s & 7;
        int chs = ch ^ (p & 7);
        int i = p >> 5, j = p & 31;
        aoff[it] = ((nimg*HP + h0 + i)*WP + (w0 + j))*256 + chs*8;
    }
    const int ldst = wave*512;   // wave-uniform LDS dest (u16), + it*2048

    // fragment-read lane constants
    const int r  = lane & 15;
    const int q4 = lane >> 4;
    const int c0k = ((q4    ) ^ (r & 7)) * 8;   // swizzled k-chunk, kk=0
    const int c1k = ((q4 + 4) ^ (r & 7)) * 8;   // kk=1
    int wm, wn;
    if (MODE == 0){ wm = wave >> 1; wn = wave & 1; } else { wm = wave; wn = 0; }
    const int aBase = (wm*(MR*16) + r)*64;
    const int cobase = (MODE==0) ? (nblk*128 + wn*64) : 0;

    // B per-lane element offsets (co row, k chunk) — add tap*COUTP*256 + kb*64 + kk*32 per step
    int bvo[NR];
    #pragma unroll
    for (int n=0;n<NR;n++) bvo[n] = (cobase + n*16 + r)*256 + q4*8;

    f32x4 acc[MR][NR];
    #pragma unroll
    for (int m=0;m<MR;m++)
        #pragma unroll
        for (int n=0;n<NR;n++)
            acc[m][n] = (f32x4)0.0f;

    auto stage = [&](int t, int b){
        int tap = t >> 2, kb = t & 3;
        int kh = tap/3, kw = tap - kh*3;
        int adel = (kh*WP + kw)*256 + kb*64;
        u16* L = lds + b*8192;
        #pragma unroll
        for (int it=0; it<4; ++it)
            g2l16(Ain + aoff[it] + adel, L + it*2048 + ldst);
    };
    auto loadB = [&](int t, f16x8 (&d)[NR][2]){
        int tap = t >> 2, kb = t & 3;
        int base = tap*COUTP*256 + kb*64;
        #pragma unroll
        for (int n=0;n<NR;n++){
            d[n][0] = *(const f16x8*)(W + base + bvo[n]);
            d[n][1] = *(const f16x8*)(W + base + bvo[n] + 32);
        }
    };

    f16x8 bA[NR][2], bB[NR][2];

    // prologue: stage A(0),A(1); load B(0); wait A(0) only (leave A(1)+B(0) in flight)
    stage(0, 0);
    stage(1, 1);
    loadB(0, bA);
    asm volatile("s_waitcnt vmcnt(%0)" :: "i"(VMN) : "memory");
    __builtin_amdgcn_s_barrier();

    auto step = [&](int t, int b, f16x8 (&use)[NR][2], f16x8 (&nxt)[NR][2]){
        const u16* L = lds + b*8192;
        f16x8 af[MR][2];
        #pragma unroll
        for (int m=0;m<MR;m++){
            af[m][0] = *(const f16x8*)(L + aBase + m*1024 + c0k);
            af[m][1] = *(const f16x8*)(L + aBase + m*1024 + c1k);
        }
        asm volatile("s_waitcnt lgkmcnt(0)" ::: "memory");   // my reads of buf[b] done
        __builtin_amdgcn_s_barrier();                        // ALL waves done reading buf[b]
        __builtin_amdgcn_sched_barrier(0);
        if (t < 34) stage(t+2, b);                           // WAR-safe overwrite
        if (t < 35) loadB(t+1, nxt);                         // regs for next step
        __builtin_amdgcn_s_setprio(1);
        #pragma unroll
        for (int n=0;n<NR;n++){
            #pragma unroll
            for (int m=0;m<MR;m++){
                acc[m][n] = __builtin_amdgcn_mfma_f32_16x16x32_f16(af[m][0], use[n][0], acc[m][n], 0,0,0);
                acc[m][n] = __builtin_amdgcn_mfma_f32_16x16x32_f16(af[m][1], use[n][1], acc[m][n], 0,0,0);
            }
        }
        __builtin_amdgcn_s_setprio(0);
        __builtin_amdgcn_sched_barrier(0);
        asm volatile("s_waitcnt vmcnt(%0)" :: "i"(VMN) : "memory");  // A(t+1) retired for my wave
        __builtin_amdgcn_s_barrier();                        // buf[b^1] fully staged
    };

    #pragma unroll 1
    for (int tt=0; tt<36; tt+=2){
        step(tt,   0, bA, bB);
        step(tt+1, 1, bB, bA);
    }

    float bcol[NR];
    #pragma unroll
    for (int n=0;n<NR;n++) bcol[n] = bias[cobase + n*16 + r];

    if (MODE == 0){
        // acc -> fp16 via LDS repack -> 16B contiguous stores (lds reused: 128x128 u16 = 32 KiB)
        #pragma unroll
        for (int m=0;m<MR;m++)
            #pragma unroll
            for (int n=0;n<NR;n++)
                #pragma unroll
                for (int jj=0;jj<4;jj++){
                    float v = fmaxf(acc[m][n][jj] + bcol[n], 0.f);
                    int p = wm*64 + m*16 + q4*4 + jj;
                    int c = wn*64 + n*16 + r;
                    lds[p*128 + c] = f2h(v);
                }
        __syncthreads();
        #pragma unroll
        for (int it=0; it<8; ++it){
            int s = it*256 + tid;
            int p = s >> 4, chh = s & 15;
            int i = p >> 5, j = p & 31;
            if (w0 + j < WW){
                size_t dst = ((size_t)((nimg*HP + h0 + i + 1)*WP + (w0 + j + 1)))*256 + nblk*128 + chh*8;
                *(u16x8*)(Oh + dst) = *(const u16x8*)(lds + p*128 + chh*8);
            }
        }
    } else {
        #pragma unroll
        for (int m=0;m<MR;m++)
            #pragma unroll
            for (int n=0;n<NR;n++)
                #pragma unroll
                for (int jj=0;jj<4;jj++){
                    float v = acc[m][n][jj] + bcol[n];
                    int p = wm*32 + m*16 + q4*4 + jj;
                    int c = n*16 + r;
                    int i = p >> 5, j = p & 31;
                    if (w0 + j < WW){
                        int pix = nimg*(HH*WW) + (h0+i)*WW + (w0+j);
                        if (MODE == 1){
                            if (c < 64)       O1[(size_t)pix*64 + c] = v;
                            else if (c == 64) O2[pix] = v;
                        } else {
                            if (c == 0) O1[pix] = v;
                        }
                    }
                }
    }
}

// ---------------- fused stat (softmax / erf-pmf / top4) + conf 1x1 convs + sigmoid*sigmoid ----------------
__global__ __launch_bounds__(256) void fuse_stat(
    const float* __restrict__ bbox, const float* __restrict__ cls_score,
    const float* __restrict__ w1, const float* __restrict__ b1,
    const float* __restrict__ w2, const float* __restrict__ b2,
    float* __restrict__ pred_cls)
{
    __shared__ float sstat[48][256];
    int tid = threadIdx.x;
    int pix = blockIdx.x*256 + tid;
    if (pix >= NPIX) return;
    const f32x4* row4 = (const f32x4*)(bbox + (size_t)pix*64);
    for (int g=0; g<4; ++g){
        f32x4 v0 = row4[g*4+0], v1 = row4[g*4+1], v2 = row4[g*4+2], v3 = row4[g*4+3];
        float lg[8], ls[8];
        #pragma unroll
        for (int k=0;k<4;k++){ lg[k]=v0[k]; lg[4+k]=v1[k]; ls[k]=v2[k]; ls[4+k]=v3[k]; }
        float m = lg[0];
        #pragma unroll
        for (int k=1;k<8;k++) m = fmaxf(m, lg[k]);
        float e[8], s = 0.f;
        #pragma unroll
        for (int k=0;k<8;k++){ e[k] = expf(lg[k]-m); s += e[k]; }
        float isum = 1.0f/s;
        float prob[8];
        #pragma unroll
        for (int k=0;k<8;k++) prob[k] = e[k]*isum;
        float pmf[8];
        #pragma unroll
        for (int k=0;k<8;k++) pmf[k] = 0.f;
        #pragma unroll
        for (int i=0;i<8;i++){
            float invi = 1.0f/(expf(ls[i]) * 1.41421356237309515f);
            float pi = prob[i];
            #pragma unroll
            for (int j=0;j<8;j++){
                float d = (float)(j - i);
                pmf[j] = fmaf(0.5f*(erff((d+1.0f)*invi) - erff((d-1.0f)*invi)), pi, pmf[j]);
            }
        }
        int used = 0;
        #pragma unroll
        for (int t=0;t<4;t++){
            float bv = -3.0e38f; int bi = 0;
            #pragma unroll
            for (int j=0;j<8;j++){
                bool ok = (((used>>j)&1)==0) && (pmf[j] > bv);
                bv = ok ? pmf[j] : bv;
                bi = ok ? j : bi;
            }
            used |= (1<<bi);
            float sl=0.f, sp=0.f;
            #pragma unroll
            for (int j=0;j<8;j++){ if (j==bi){ sl=ls[j]; sp=prob[j]; } }
            sstat[g*4+t][tid]    = sl;
            sstat[16+g*4+t][tid] = sp;
            sstat[32+g*4+t][tid] = bv;
        }
    }
    float q = b2[0];
    for (int u=0; u<64; ++u){
        float h = b1[u];
        #pragma unroll
        for (int c=0;c<48;c++) h = fmaf(sstat[c][tid], w1[u*48+c], h);
        q = fmaf(fmaxf(h,0.f), w2[u], q);
    }
    float quality = 1.0f/(1.0f+expf(-q));
    float cs = cls_score[pix];
    pred_cls[pix] = quality/(1.0f+expf(-cs));
}

// ---------------- launch ----------------
extern "C" void kernel_launch(void* const* d_in, const int* in_sizes, int n_in,
                              void* d_out, int out_size, void* d_ws, size_t ws_size,
                              hipStream_t stream) {
    (void)in_sizes; (void)n_in; (void)out_size;
    const float* feature = (const float*)d_in[0];
    const float* cls_w   = (const float*)d_in[1];
    const float* cls_b   = (const float*)d_in[2];
    const float* box_w   = (const float*)d_in[3];
    const float* box_b   = (const float*)d_in[4];
    const float* score_w = (const float*)d_in[5];
    const float* score_b = (const float*)d_in[6];
    const float* pred_w  = (const float*)d_in[7];
    const float* pred_b  = (const float*)d_in[8];
    const float* ctn_w   = (const float*)d_in[9];
    const float* ctn_b   = (const float*)d_in[10];
    const float* conf_w1 = (const float*)d_in[11];
    const float* conf_b1 = (const float*)d_in[12];
    const float* conf_w2 = (const float*)d_in[13];
    const float* conf_b2 = (const float*)d_in[14];

    float* out      = (float*)d_out;
    float* pred_cls = out;
    float* pred_reg = out + NPIX;
    float* pred_ctn = out + NPIX + (size_t)NPIX*64;

    char* ws = (char*)d_ws;
    size_t off = 0;
    auto alloc = [&](size_t b){ size_t rr = off; off += (b + 255) & ~(size_t)255; return rr; };
    u16* aA = (u16*)(ws + alloc(ACT_BYTES));
    u16* aB = (u16*)(ws + alloc(ACT_BYTES));
    const size_t TWR = (size_t)4*9*256*256;   // tower wt elements
    u16* wCls = (u16*)(ws + alloc(TWR*2));
    u16* wBox = (u16*)(ws + alloc(TWR*2));
    u16* wSc  = (u16*)(ws + alloc((size_t)9*16*256*2));
    u16* wPc  = (u16*)(ws + alloc((size_t)9*80*256*2));
    float* bPc = (float*)(ws + alloc(128*4));
    float* bSc = (float*)(ws + alloc(128*4));
    float* clsScore = (float*)(ws + alloc((size_t)NPIX*4));
    if (ws_size < off) return;   // insufficient workspace: bail (bench will flag)

    dim3 B(256);
    // prep
    zero_borders<<<508, B, 0, stream>>>(aA, aB);
    wt_tower<<<9216, B, 0, stream>>>(cls_w, wCls);
    wt_tower<<<9216, B, 0, stream>>>(box_w, wBox);
    wt_score<<<144, B, 0, stream>>>(score_w, wSc);
    wt_predctn<<<720, B, 0, stream>>>(pred_w, ctn_w, wPc);
    prep_bias<<<1, 128, 0, stream>>>(pred_b, ctn_b, score_b, bPc, bSc);

    const size_t LW = (size_t)9*256*256;      // per-layer tower wt elements
    // cls tower: feat->A, A->B->A->B->A  (B is clobbered along the way — box tower
    // re-materializes its own input below; do NOT share the feature copy)
    feat2act<<<9600, B, 0, stream>>>(feature, aA);
    conv3x3_k<0><<<2000, B, 0, stream>>>(aA, wCls+0*LW, cls_b+0*256, aB, nullptr, nullptr, 2, 256);
    conv3x3_k<0><<<2000, B, 0, stream>>>(aB, wCls+1*LW, cls_b+1*256, aA, nullptr, nullptr, 2, 256);
    conv3x3_k<0><<<2000, B, 0, stream>>>(aA, wCls+2*LW, cls_b+2*256, aB, nullptr, nullptr, 2, 256);
    conv3x3_k<0><<<2000, B, 0, stream>>>(aB, wCls+3*LW, cls_b+3*256, aA, nullptr, nullptr, 2, 256);
    // score head (reads x4 in A)
    conv3x3_k<2><<<1000, B, 0, stream>>>(aA, wSc, bSc, nullptr, clsScore, nullptr, 1, 16);
    // box tower: feat->B, B->A->B->A->B
    feat2act<<<9600, B, 0, stream>>>(feature, aB);
    conv3x3_k<0><<<2000, B, 0, stream>>>(aB, wBox+0*LW, box_b+0*256, aA, nullptr, nullptr, 2, 256);
    conv3x3_k<0><<<2000, B, 0, stream>>>(aA, wBox+1*LW, box_b+1*256, aB, nullptr, nullptr, 2, 256);
    conv3x3_k<0><<<2000, B, 0, stream>>>(aB, wBox+2*LW, box_b+2*256, aA, nullptr, nullptr, 2, 256);
    conv3x3_k<0><<<2000, B, 0, stream>>>(aA, wBox+3*LW, box_b+3*256, aB, nullptr, nullptr, 2, 256);
    // pred + ctn head (reads y4 in B) -> writes pred_reg / pred_ctn directly
    conv3x3_k<1><<<1000, B, 0, stream>>>(aB, wPc, bPc, nullptr, pred_reg, pred_ctn, 1, 80);
    // fused stat + conf + final cls
    fuse_stat<<<475, B, 0, stream>>>(pred_reg, clsScore, conf_w1, conf_b1, conf_w2, conf_b2, pred_cls);
}

// Round 7
// 1957.411 us; speedup vs baseline: 1.4630x; 1.4630x over previous
//
#include <hip/hip_runtime.h>

typedef unsigned short u16;
typedef _Float16 f16;
typedef __attribute__((ext_vector_type(4))) float f32x4;
typedef __attribute__((ext_vector_type(8))) _Float16 f16x8;
typedef __attribute__((ext_vector_type(8))) unsigned short u16x8;

#define NIMG 8
#define HH 100
#define WW 152
#define HP 102
#define WP 154
#define NPIX (NIMG*HH*WW)                       // 121600
#define ACT_ELEMS ((size_t)NIMG*HP*WP*256)      // 32,169,984
#define ACT_BYTES (ACT_ELEMS*2)

// conv LDS map (u16 units): halo A [<=352 px][64 ch] then 2 B buffers [128 co][64 k]
#define HALO_U16 22528      // 45056 B
#define BBUF_U16 8192       // 16 KB per B buffer
#define LDS_U16  38912      // 77824 B total (2 blocks/CU at 160 KB)

__device__ __forceinline__ u16 f2h(float x){
    f16 h = (f16)x;                       // v_cvt_f16_f32, RNE
    return __builtin_bit_cast(u16, h);
}

__device__ __forceinline__ void g2l16(const u16* g, u16* l){
    __builtin_amdgcn_global_load_lds((const __attribute__((address_space(1))) unsigned int*)g,
                                     (__attribute__((address_space(3))) unsigned int*)l, 16, 0, 0);
}

// ---------------- border zeroing (pads of both ping-pong activation buffers) ----------------
__global__ void zero_borders(u16* A, u16* B){
    int id = blockIdx.x*256 + threadIdx.x;            // 8*508*32 = 130048 exact
    int ch = id & 31; int t = id >> 5;
    int pb = t % 508; int nimg = t / 508;
    int hp, wp;
    if (pb < 154)      { hp = 0;            wp = pb; }
    else if (pb < 308) { hp = 101;          wp = pb - 154; }
    else if (pb < 408) { hp = pb - 308 + 1; wp = 0; }
    else               { hp = pb - 408 + 1; wp = 153; }
    size_t off = ((size_t)((nimg*HP + hp)*WP + wp))*256 + ch*8;
    u16x8 z = {};
    *(u16x8*)(A+off) = z; *(u16x8*)(B+off) = z;
}

// ---------------- NCHW fp32 feature -> padded NHWC fp16 ----------------
__global__ void feat2act(const float* __restrict__ F, u16* __restrict__ D){
    __shared__ float t[64][65];
    int bid = blockIdx.x;
    int wb = bid % 3; bid /= 3;
    int cb = bid & 3; bid >>= 2;
    int h = bid % 100; int nimg = bid / 100;
    int c0 = cb*64, w0 = wb*64;
    int tid = threadIdx.x;
    int cl = tid >> 6;
    int wl = tid & 63;
    #pragma unroll
    for (int rr=0; rr<16; ++rr){
        int c = rr*4 + cl;
        int w = w0 + wl;
        float v = 0.f;
        if (w < WW) v = F[ ((size_t)((nimg*256 + c0 + c)*HH + h))*WW + w ];
        t[c][wl] = v;
    }
    __syncthreads();
    int wl2 = tid >> 6;
    int cl2 = tid & 63;
    #pragma unroll
    for (int rr=0; rr<16; ++rr){
        int w = rr*4 + wl2;
        if (w0 + w < WW){
            size_t dst = ((size_t)((nimg*HP + h + 1)*WP + (w0 + w + 1)))*256 + c0 + cl2;
            D[dst] = f2h(t[cl2][w]);
        }
    }
}

// ---------------- weight transforms: OIHW fp32 -> [tap][co][ci] fp16 ----------------
__global__ void wt_tower(const float* __restrict__ src, u16* __restrict__ d){
    int idx = blockIdx.x*256 + threadIdx.x;        // layers*9*256*256, exact
    int ci = idx & 255; int t = idx >> 8;
    int co = t & 255; t >>= 8;
    int tap = t % 9; int l = t / 9;
    d[idx] = f2h(src[ ((size_t)((l*256+co)*256+ci))*9 + tap ]);
}
// pred(64)+ctn(1) padded to 128 cout
__global__ void wt_predctn(const float* __restrict__ pw, const float* __restrict__ cw,
                           u16* __restrict__ d){
    int idx = blockIdx.x*256 + threadIdx.x;        // 9*128*256 exact (1152 blocks)
    int ci = idx & 255; int co = (idx>>8) & 127; int tap = idx >> 15;
    float v = 0.f;
    if (co < 64)       v = pw[ ((size_t)(co*256+ci))*9 + tap ];
    else if (co == 64) v = cw[ (size_t)ci*9 + tap ];
    d[idx] = f2h(v);
}
// score(1) padded to 128 cout
__global__ void wt_score(const float* __restrict__ sw, u16* __restrict__ d){
    int idx = blockIdx.x*256 + threadIdx.x;        // 9*128*256 exact (1152 blocks)
    int ci = idx & 255; int co = (idx>>8) & 127; int tap = idx >> 15;
    d[idx] = f2h((co == 0) ? sw[ (size_t)ci*9 + tap ] : 0.f);
}
__global__ void prep_bias(const float* pb, const float* cb, const float* sb, float* bpc, float* bsc){
    int i = threadIdx.x;      // 128
    bpc[i] = (i < 64) ? pb[i] : ((i == 64) ? cb[0] : 0.f);
    bsc[i] = (i == 0) ? sb[0] : 0.f;
}

// ---------------- conv3x3 implicit GEMM, fp16, 256px x 128co tile, halo-A staging ----------------
// 512 threads = 8 waves (4M x 2N); per wave 64px x 64co (MR=4, NR=4), K-step 64.
// A: halo tile (10 x 34 px x 64ch, chunk-swizzled) staged ONCE per kb (9 tap-steps reuse it).
// B: [128co][64k] double-buffered per tap-step (chunk-swizzled), via global_load_lds.
// Step: ds_read frags -> lgkmcnt(0) -> barrier -> [restage halo if tap==8] -> stageB(t+2)
//       -> MFMA -> vmcnt(2) (counted: leaves B(t+2) in flight) -> barrier.
// MODE 0: tower (relu, store padded NHWC fp16);  MODE 1: pred+ctn;  MODE 2: score.
template<int MODE>
__global__ __launch_bounds__(512, 2) void conv3x3_k(
    const u16* __restrict__ Ain, const u16* __restrict__ W,
    const float* __restrict__ bias,
    u16* __restrict__ Oh, float* __restrict__ O1, float* __restrict__ O2,
    int NB, int COUTP)
{
    __shared__ u16 lds[LDS_U16];
    const int tid  = threadIdx.x;
    const int lane = tid & 63;
    const int wave = tid >> 6;

    // bijective XCD swizzle (gridDim.x % 8 == 0)
    int nwg = gridDim.x;
    int bid = blockIdx.x;
    int qq  = nwg >> 3;
    int swz = (bid & 7)*qq + (bid >> 3);
    int nblk = swz % NB;
    int mblk = swz / NB;
    int nimg = mblk / 65;
    int rem  = mblk - nimg*65;
    int ht   = rem / 5;
    int wt5  = rem - ht*5;
    int h0 = ht*8, w0 = wt5*32;          // h0,w0 in padded coords (halo origin)
    int co0 = nblk*128;

    // halo staging consts: slot s = it*512+tid (2720 active of 3072); p=s>>3 halo-pixel,
    // ch=s&7; swizzled source chunk chs = ch ^ (p&7); p -> (hh=p/34, ww=p%34)
    int hsrc[6];
    #pragma unroll
    for (int it=0; it<6; ++it){
        int s = it*512 + tid;
        int p = s >> 3, ch = s & 7;
        int chs = ch ^ (p & 7);
        int hh = p / 34, ww = p - hh*34;
        int row = h0 + hh; if (row > 101) row = 101;     // clamp (bottom tiles)
        hsrc[it] = ((nimg*HP + row)*WP + (w0 + ww))*256 + chs*8;
    }
    // B staging consts: 1024 slots = 2 its; p=s>>3 co-row, chs = ch ^ (p&7)
    int bsrc[2];
    #pragma unroll
    for (int it=0; it<2; ++it){
        int s = it*512 + tid;
        int p = s >> 3, ch = s & 7;
        int chs = ch ^ (p & 7);
        bsrc[it] = (co0 + p)*256 + chs*8;
    }
    const int wofs = wave*512;           // u16, + it*4096 per staging iter

    // fragment-read lane constants
    const int r  = lane & 15;
    const int q4 = lane >> 4;
    const int mg = wave >> 1;            // 0..3 (64-px row group)
    const int wn = wave & 1;             // co half
    const int laneHBase = mg*68 + r;     // (mg*2)*34 + r ; + kh*34+kw per tap
    const int bRead = (wn*64 + r)*64 + (q4 ^ (r & 7))*8;   // u16; kk=1 via ^32; n via +n*1024

    f32x4 acc[4][4];
    #pragma unroll
    for (int m=0;m<4;m++)
        #pragma unroll
        for (int n=0;n<4;n++)
            acc[m][n] = (f32x4)0.0f;

    auto stageHalo = [&](int kb){
        int kofs = kb*64;
        u16* L = lds + wofs;
        #pragma unroll
        for (int it=0; it<5; ++it)
            g2l16(Ain + hsrc[it] + kofs, L + it*4096);
        if (tid < 160) g2l16(Ain + hsrc[5] + kofs, L + 5*4096);
    };
    auto stageB = [&](int tap2, int kb2, int buf){
        int wb = tap2*COUTP*256 + kb2*64;
        u16* L = lds + HALO_U16 + buf*BBUF_U16 + wofs;
        #pragma unroll
        for (int it=0; it<2; ++it)
            g2l16(W + wb + bsrc[it], L + it*4096);
    };

    // prologue: halo(kb=0) + B(0)->buf0 + B(1)->buf1; wait halo+B0, leave B1 in flight
    stageHalo(0);
    stageB(0, 0, 0);
    stageB(1, 0, 1);
    asm volatile("s_waitcnt vmcnt(2)" ::: "memory");
    __builtin_amdgcn_s_barrier();

    #pragma unroll 1
    for (int t=0; t<36; ++t){
        int kb  = t/9;
        int tap = t - kb*9;
        int kh  = tap/3;
        int kw  = tap - kh*3;
        // A fragment addresses (u16) from halo, tap-shifted, swizzle-corrected
        int hp  = laneHBase + kh*34 + kw;
        int aA  = hp*64  + (q4 ^ (hp  & 7))*8;     // m=0 (kk0); m=1 at +1024
        int hp2 = hp + 34;
        int aB  = hp2*64 + (q4 ^ (hp2 & 7))*8;     // m=2 (kk0); m=3 at +1024
        const u16* Lb = lds + HALO_U16 + (t & 1)*BBUF_U16;

        f16x8 af[4][2], bf[4][2];
        af[0][0] = *(const f16x8*)(lds + aA);
        af[0][1] = *(const f16x8*)(lds + (aA ^ 32));
        af[1][0] = *(const f16x8*)(lds + aA + 1024);
        af[1][1] = *(const f16x8*)(lds + (aA ^ 32) + 1024);
        af[2][0] = *(const f16x8*)(lds + aB);
        af[2][1] = *(const f16x8*)(lds + (aB ^ 32));
        af[3][0] = *(const f16x8*)(lds + aB + 1024);
        af[3][1] = *(const f16x8*)(lds + (aB ^ 32) + 1024);
        #pragma unroll
        for (int n=0;n<4;n++){
            bf[n][0] = *(const f16x8*)(Lb + bRead + n*1024);
            bf[n][1] = *(const f16x8*)(Lb + (bRead ^ 32) + n*1024);
        }
        asm volatile("s_waitcnt lgkmcnt(0)" ::: "memory");   // my reads done
        __builtin_amdgcn_s_barrier();                        // all waves done reading
        __builtin_amdgcn_sched_barrier(0);
        if (tap == 8 && kb < 3) stageHalo(kb+1);             // halo safe to overwrite now
        if (t < 34){
            int tn = t + 2;
            int kbn = tn/9;
            stageB(tn - kbn*9, kbn, t & 1);                  // overwrite Bbuf[t&1]
        }
        __builtin_amdgcn_s_setprio(1);
        #pragma unroll
        for (int n=0;n<4;n++){
            #pragma unroll
            for (int m=0;m<4;m++){
                acc[m][n] = __builtin_amdgcn_mfma_f32_16x16x32_f16(af[m][0], bf[n][0], acc[m][n], 0,0,0);
                acc[m][n] = __builtin_amdgcn_mfma_f32_16x16x32_f16(af[m][1], bf[n][1], acc[m][n], 0,0,0);
            }
        }
        __builtin_amdgcn_s_setprio(0);
        __builtin_amdgcn_sched_barrier(0);
        // counted wait: B(t+1) (and halo, if restaged) landed; B(t+2) stays in flight
        if (t < 34) { asm volatile("s_waitcnt vmcnt(2)" ::: "memory"); }
        else        { asm volatile("s_waitcnt vmcnt(0)" ::: "memory"); }
        __builtin_amdgcn_s_barrier();
    }

    float bcol[4];
    #pragma unroll
    for (int n=0;n<4;n++) bcol[n] = bias[co0 + wn*64 + n*16 + r];

    if (MODE == 0){
        // acc -> fp16 via LDS repack (stride 132 u16 kills q4-group bank aliasing) -> 16B stores
        #pragma unroll
        for (int m=0;m<4;m++)
            #pragma unroll
            for (int n=0;n<4;n++)
                #pragma unroll
                for (int jj=0;jj<4;jj++){
                    float v = fmaxf(acc[m][n][jj] + bcol[n], 0.f);
                    int p = mg*64 + m*16 + q4*4 + jj;
                    int c = wn*64 + n*16 + r;
                    lds[p*132 + c] = f2h(v);
                }
        __syncthreads();
        #pragma unroll
        for (int it=0; it<8; ++it){
            int s = it*512 + tid;
            int p = s >> 4, chh = s & 15;
            int i = p >> 5, j = p & 31;
            if (h0 + i < HH && w0 + j < WW){
                size_t dst = ((size_t)((nimg*HP + h0 + i + 1)*WP + (w0 + j + 1)))*256 + co0 + chh*8;
                *(u16x8*)(Oh + dst) = *(const u16x8*)(lds + p*132 + chh*8);
            }
        }
    } else {
        #pragma unroll
        for (int m=0;m<4;m++)
            #pragma unroll
            for (int n=0;n<4;n++)
                #pragma unroll
                for (int jj=0;jj<4;jj++){
                    float v = acc[m][n][jj] + bcol[n];
                    int p = mg*64 + m*16 + q4*4 + jj;
                    int c = wn*64 + n*16 + r;
                    int i = p >> 5, j = p & 31;
                    if (h0 + i < HH && w0 + j < WW){
                        int pix = nimg*(HH*WW) + (h0+i)*WW + (w0+j);
                        if (MODE == 1){
                            if (c < 64)       O1[(size_t)pix*64 + c] = v;
                            else if (c == 64) O2[pix] = v;
                        } else {
                            if (c == 0) O1[pix] = v;
                        }
                    }
                }
    }
}

// ---------------- fused stat (softmax / erf-pmf / top4) + conf 1x1 convs + sigmoid*sigmoid ----------------
__global__ __launch_bounds__(256) void fuse_stat(
    const float* __restrict__ bbox, const float* __restrict__ cls_score,
    const float* __restrict__ w1, const float* __restrict__ b1,
    const float* __restrict__ w2, const float* __restrict__ b2,
    float* __restrict__ pred_cls)
{
    __shared__ float sstat[48][256];
    int tid = threadIdx.x;
    int pix = blockIdx.x*256 + tid;
    if (pix >= NPIX) return;
    const f32x4* row4 = (const f32x4*)(bbox + (size_t)pix*64);
    for (int g=0; g<4; ++g){
        f32x4 v0 = row4[g*4+0], v1 = row4[g*4+1], v2 = row4[g*4+2], v3 = row4[g*4+3];
        float lg[8], ls[8];
        #pragma unroll
        for (int k=0;k<4;k++){ lg[k]=v0[k]; lg[4+k]=v1[k]; ls[k]=v2[k]; ls[4+k]=v3[k]; }
        float m = lg[0];
        #pragma unroll
        for (int k=1;k<8;k++) m = fmaxf(m, lg[k]);
        float e[8], s = 0.f;
        #pragma unroll
        for (int k=0;k<8;k++){ e[k] = expf(lg[k]-m); s += e[k]; }
        float isum = 1.0f/s;
        float prob[8];
        #pragma unroll
        for (int k=0;k<8;k++) prob[k] = e[k]*isum;
        float pmf[8];
        #pragma unroll
        for (int k=0;k<8;k++) pmf[k] = 0.f;
        #pragma unroll
        for (int i=0;i<8;i++){
            float invi = 1.0f/(expf(ls[i]) * 1.41421356237309515f);
            float pi = prob[i];
            #pragma unroll
            for (int j=0;j<8;j++){
                float d = (float)(j - i);
                pmf[j] = fmaf(0.5f*(erff((d+1.0f)*invi) - erff((d-1.0f)*invi)), pi, pmf[j]);
            }
        }
        int used = 0;
        #pragma unroll
        for (int t=0;t<4;t++){
            float bv = -3.0e38f; int bi = 0;
            #pragma unroll
            for (int j=0;j<8;j++){
                bool ok = (((used>>j)&1)==0) && (pmf[j] > bv);
                bv = ok ? pmf[j] : bv;
                bi = ok ? j : bi;
            }
            used |= (1<<bi);
            float sl=0.f, sp=0.f;
            #pragma unroll
            for (int j=0;j<8;j++){ if (j==bi){ sl=ls[j]; sp=prob[j]; } }
            sstat[g*4+t][tid]    = sl;
            sstat[16+g*4+t][tid] = sp;
            sstat[32+g*4+t][tid] = bv;
        }
    }
    float q = b2[0];
    for (int u=0; u<64; ++u){
        float h = b1[u];
        #pragma unroll
        for (int c=0;c<48;c++) h = fmaf(sstat[c][tid], w1[u*48+c], h);
        q = fmaf(fmaxf(h,0.f), w2[u], q);
    }
    float quality = 1.0f/(1.0f+expf(-q));
    float cs = cls_score[pix];
    pred_cls[pix] = quality/(1.0f+expf(-cs));
}

// ---------------- launch ----------------
extern "C" void kernel_launch(void* const* d_in, const int* in_sizes, int n_in,
                              void* d_out, int out_size, void* d_ws, size_t ws_size,
                              hipStream_t stream) {
    (void)in_sizes; (void)n_in; (void)out_size;
    const float* feature = (const float*)d_in[0];
    const float* cls_w   = (const float*)d_in[1];
    const float* cls_b   = (const float*)d_in[2];
    const float* box_w   = (const float*)d_in[3];
    const float* box_b   = (const float*)d_in[4];
    const float* score_w = (const float*)d_in[5];
    const float* score_b = (const float*)d_in[6];
    const float* pred_w  = (const float*)d_in[7];
    const float* pred_b  = (const float*)d_in[8];
    const float* ctn_w   = (const float*)d_in[9];
    const float* ctn_b   = (const float*)d_in[10];
    const float* conf_w1 = (const float*)d_in[11];
    const float* conf_b1 = (const float*)d_in[12];
    const float* conf_w2 = (const float*)d_in[13];
    const float* conf_b2 = (const float*)d_in[14];

    float* out      = (float*)d_out;
    float* pred_cls = out;
    float* pred_reg = out + NPIX;
    float* pred_ctn = out + NPIX + (size_t)NPIX*64;

    char* ws = (char*)d_ws;
    size_t off = 0;
    auto alloc = [&](size_t b){ size_t rr = off; off += (b + 255) & ~(size_t)255; return rr; };
    u16* aA = (u16*)(ws + alloc(ACT_BYTES + 65536));   // slack: clamped halo over-reads
    u16* aB = (u16*)(ws + alloc(ACT_BYTES + 65536));
    const size_t TWR = (size_t)4*9*256*256;   // tower wt elements
    const size_t HDW = (size_t)9*128*256;     // head wt elements (128-padded)
    u16* wCls = (u16*)(ws + alloc(TWR*2));
    u16* wBox = (u16*)(ws + alloc(TWR*2));
    u16* wSc  = (u16*)(ws + alloc(HDW*2));
    u16* wPc  = (u16*)(ws + alloc(HDW*2));
    float* bPc = (float*)(ws + alloc(128*4));
    float* bSc = (float*)(ws + alloc(128*4));
    float* clsScore = (float*)(ws + alloc((size_t)NPIX*4));
    if (ws_size < off) return;   // insufficient workspace: bail (bench will flag)

    dim3 B(256);
    // prep
    zero_borders<<<508, B, 0, stream>>>(aA, aB);
    wt_tower<<<9216, B, 0, stream>>>(cls_w, wCls);
    wt_tower<<<9216, B, 0, stream>>>(box_w, wBox);
    wt_score<<<1152, B, 0, stream>>>(score_w, wSc);
    wt_predctn<<<1152, B, 0, stream>>>(pred_w, ctn_w, wPc);
    prep_bias<<<1, 128, 0, stream>>>(pred_b, ctn_b, score_b, bPc, bSc);

    const size_t LW = (size_t)9*256*256;      // per-layer tower wt elements
    dim3 CB(512);
    // cls tower: feat->A, A->B->A->B->A  (box tower re-materializes its own input below)
    feat2act<<<9600, B, 0, stream>>>(feature, aA);
    conv3x3_k<0><<<1040, CB, 0, stream>>>(aA, wCls+0*LW, cls_b+0*256, aB, nullptr, nullptr, 2, 256);
    conv3x3_k<0><<<1040, CB, 0, stream>>>(aB, wCls+1*LW, cls_b+1*256, aA, nullptr, nullptr, 2, 256);
    conv3x3_k<0><<<1040, CB, 0, stream>>>(aA, wCls+2*LW, cls_b+2*256, aB, nullptr, nullptr, 2, 256);
    conv3x3_k<0><<<1040, CB, 0, stream>>>(aB, wCls+3*LW, cls_b+3*256, aA, nullptr, nullptr, 2, 256);
    // score head (reads x4 in A)
    conv3x3_k<2><<<520, CB, 0, stream>>>(aA, wSc, bSc, nullptr, clsScore, nullptr, 1, 128);
    // box tower: feat->B, B->A->B->A->B
    feat2act<<<9600, B, 0, stream>>>(feature, aB);
    conv3x3_k<0><<<1040, CB, 0, stream>>>(aB, wBox+0*LW, box_b+0*256, aA, nullptr, nullptr, 2, 256);
    conv3x3_k<0><<<1040, CB, 0, stream>>>(aA, wBox+1*LW, box_b+1*256, aB, nullptr, nullptr, 2, 256);
    conv3x3_k<0><<<1040, CB, 0, stream>>>(aB, wBox+2*LW, box_b+2*256, aA, nullptr, nullptr, 2, 256);
    conv3x3_k<0><<<1040, CB, 0, stream>>>(aA, wBox+3*LW, box_b+3*256, aB, nullptr, nullptr, 2, 256);
    // pred + ctn head (reads y4 in B) -> writes pred_reg / pred_ctn directly
    conv3x3_k<1><<<520, CB, 0, stream>>>(aB, wPc, bPc, nullptr, pred_reg, pred_ctn, 1, 128);
    // fused stat + conf + final cls
    fuse_stat<<<475, B, 0, stream>>>(pred_reg, clsScore, conf_w1, conf_b1, conf_w2, conf_b2, pred_cls);
}